// Round 7
// baseline (255.166 us; speedup 1.0000x reference)
//
#include <hip/hip_runtime.h>
#include <math.h>

#define B_   32
#define C_   32
#define T_   1024
#define NF_  33
#define F2_  66      // NF*2
#define FD_  2112    // C_*F2_
#define NW_  961
#define MLP_ 256
#define HID_ 256
#define HH_  128

#define PI_F     3.14159265358979323846f
#define LN2_F    0.69314718055994530942f
#define L2E2_F   2.88539008177792681472f   // 2*log2(e)

typedef unsigned short u16;
typedef unsigned int   u32;
typedef __attribute__((ext_vector_type(8))) short bf16x8;
typedef __attribute__((ext_vector_type(4))) float f32x4;

__device__ __forceinline__ u16 f2bf(float f) {
    u32 u = __float_as_uint(f);
    u = u + 0x7FFFu + ((u >> 16) & 1u);   // RNE
    return (u16)(u >> 16);
}
__device__ __forceinline__ float bf2f(u16 h) {
    return __uint_as_float((u32)h << 16);
}
__device__ __forceinline__ void gload16(const void* g, void* l) {
    __builtin_amdgcn_global_load_lds(
        (const __attribute__((address_space(1))) void*)g,
        (__attribute__((address_space(3))) void*)l, 16, 0, 0);
}
__device__ __forceinline__ float ftanh(float x) {
    float z = __builtin_amdgcn_exp2f(x * L2E2_F);
    return 1.f - 2.f * __builtin_amdgcn_rcpf(z + 1.f);
}
__device__ __forceinline__ float flog1p(float x) {
    return __builtin_amdgcn_logf(1.f + x) * LN2_F;   // v_log_f32 is log2
}
// atan2(y,x)/pi, poly max err ~2e-6 (in pi units)
__device__ __forceinline__ float fatan2pi(float y, float x) {
    const float ay = fabsf(y), ax = fabsf(x);
    const float mn = fminf(ay, ax), mx = fmaxf(ay, ax);
    float t = mn * __builtin_amdgcn_rcpf(mx);
    t = (mx == 0.f) ? 0.f : t;
    const float s = t * t;
    float p = -0.00373098f;
    p = fmaf(p, s,  0.01676008f);
    p = fmaf(p, s, -0.03706162f);
    p = fmaf(p, s,  0.06160679f);
    p = fmaf(p, s, -0.10587735f);
    p = fmaf(p, s,  0.31830265f);
    p *= t;
    p = (ay > ax) ? 0.5f - p : p;
    p = (x < 0.f) ? 1.0f - p : p;
    return copysignf(p, y);
}

// ---------------------------------------------------------------------------
// wconv: fp32 weight matrix -> bf16 hi/lo planes (same layout)  [W1, W2]
// ---------------------------------------------------------------------------
__global__ __launch_bounds__(256) void wconv_kernel(const float* __restrict__ W,
                                                    u16* __restrict__ WH,
                                                    u16* __restrict__ WL,
                                                    int total) {
    for (int i = blockIdx.x * 256 + threadIdx.x; i < total; i += gridDim.x * 256) {
        const float v = W[i];
        const u16 h = f2bf(v);
        WH[i] = h;
        WL[i] = f2bf(v - bf2f(h));
    }
}

// ---------------------------------------------------------------------------
// wconvP: Wp [256][2112] -> bf16 hi/lo in K-PERMUTED layout:
// dst col' = q*32 + c  where src col = c*66 + q  (q = 2f+p).
// A K-step of 32 then equals {all 32 channels} at fixed (bin, mag/ph).
// ---------------------------------------------------------------------------
__global__ __launch_bounds__(256) void wconvP_kernel(const float* __restrict__ W,
                                                     u16* __restrict__ PH,
                                                     u16* __restrict__ PL) {
    const int total = MLP_ * FD_;
    for (int i = blockIdx.x * 256 + threadIdx.x; i < total; i += gridDim.x * 256) {
        const int n = i / FD_;
        const int kk = i - n * FD_;
        const int c = kk / F2_;
        const int q = kk - c * F2_;
        const float v = W[i];                      // coalesced read
        const u16 h = f2bf(v);
        const int d = n * FD_ + q * 32 + c;        // scattered write (one-time)
        PH[d] = h;
        PL[d] = f2bf(v - bf2f(h));
    }
}

// ---------------------------------------------------------------------------
// softmax(agg) -> wts (single block)
// ---------------------------------------------------------------------------
__global__ __launch_bounds__(256) void softmax_kernel(const float* __restrict__ agg,
                                                      float* __restrict__ wts) {
    const int tid = threadIdx.x;
    __shared__ float red[256];
    float mx = -INFINITY;
    for (int i = tid; i < NW_; i += 256) mx = fmaxf(mx, agg[i]);
    red[tid] = mx; __syncthreads();
    for (int s = 128; s > 0; s >>= 1) {
        if (tid < s) red[tid] = fmaxf(red[tid], red[tid + s]);
        __syncthreads();
    }
    mx = red[0]; __syncthreads();
    float sm = 0.f;
    for (int i = tid; i < NW_; i += 256) sm += expf(agg[i] - mx);
    red[tid] = sm; __syncthreads();
    for (int s = 128; s > 0; s >>= 1) {
        if (tid < s) red[tid] += red[tid + s];
        __syncthreads();
    }
    const float inv = 1.f / red[0];
    for (int i = tid; i < NW_; i += 256) wts[i] = expf(agg[i] - mx) * inv;
}

// ---------------------------------------------------------------------------
// fused feat+proj: grid (8 window-tiles, nb batches), 512 thr / 8 waves (2x4,
// wave tile 64x64, BM=128, BN=256). Per bin f in [0,33):
//   1) issue B-loads: WpP hi/lo for K-steps q=2f,2f+1 (L2-resident)
//   2) gen: thread (c, chain) computes 8 windows of bin f via sliding DFT
//      with its 72 x-samples in REGISTERS; writes bf16 mag/ph A-chunks
//      (128x32 each, XOR-swizzled) into LDS
//   3) barrier; MFMA 2 K-steps x 4x4 frags x 2 terms (Ah*Bh + Ah*Bl)
// Nyquist f=32: exact-real bin -> ph = (re<0) (np.angle convention).
// Epilogue: proj = tanh(acc + bp)*pi -> bf16 hi/lo planes.
// ---------------------------------------------------------------------------
#define OFF_XS  512
#define OFF_A   25344                    // 512 + 32*194*4
#define OFF_A2  (OFF_A + 8192)
#define OFF_B   (OFF_A + 16384)         // 41728
#define LDS_TOT (OFF_B + 65536)         // 107264

__global__ __launch_bounds__(512, 2) void fused_feat_proj_kernel(
        const float* __restrict__ x,
        const u16* __restrict__ WpPH, const u16* __restrict__ WpPL,
        const float* __restrict__ bp,
        u16* __restrict__ projH, u16* __restrict__ projL) {
    const int tile = blockIdx.x;
    const int bb   = blockIdx.y;
    const int n0   = tile * 128;
    const int tid  = threadIdx.x;
    const int lane = tid & 63, w = tid >> 6;
    const int wr = w >> 2, wc = w & 3;        // 2 x 4 waves of 64x64
    const int mval = (NW_ - n0 < 128) ? (NW_ - n0) : 128;

    __shared__ char lds[LDS_TOT];
    float2* stabv = (float2*)lds;
    float*  xsf   = (float*)(lds + OFF_XS);   // [32][194] padded fp32

    if (tid < 64) {
        float s, cc;
        sincosf(-PI_F * (float)tid / 32.0f, &s, &cc);
        stabv[tid] = make_float2(cc, s);      // (cos, sin) of -pi*m/32
    }
    // xs fill: 32 ch x 192 samples (zero past T_)
    {
        const int cF = tid >> 4, sF = tid & 15;
        const float* xb = x + ((size_t)bb * C_ + cF) * T_;
#pragma unroll
        for (int ii = 0; ii < 3; ++ii) {
            const int j = sF * 12 + ii * 4;
            const int t = n0 + j;
            float4 v = {0.f, 0.f, 0.f, 0.f};
            if (t + 3 < T_) {
                v = *(const float4*)(xb + t);
            } else {
                if (t + 0 < T_) v.x = xb[t + 0];
                if (t + 1 < T_) v.y = xb[t + 1];
                if (t + 2 < T_) v.z = xb[t + 2];
            }
            float* d = xsf + cF * 194 + j;
            d[0] = v.x; d[1] = v.y; d[2] = v.z; d[3] = v.w;
        }
    }
    __syncthreads();

    // pull this thread's window samples into registers (all-static indexing)
    const int cch = tid & 31, wch = tid >> 5;
    const int ws = wch * 8;                   // local window-chain start row
    float xr[72];
    {
        const float* xrow = xsf + cch * 194 + ws;
#pragma unroll
        for (int k = 0; k < 72; ++k) xr[k] = xrow[k];
    }

    f32x4 acc[4][4];
#pragma unroll
    for (int i = 0; i < 4; ++i)
#pragma unroll
        for (int j = 0; j < 4; ++j) acc[i][j] = (f32x4){0.f, 0.f, 0.f, 0.f};

    // B staging constants (involution swizzle, rule-21 both-sides)
    const int srow0 = tid >> 2, slot = tid & 3;
    const int srow1 = srow0 + 128;
    const int kc0 = slot ^ ((srow0 >> 1) & 3);
    const int kc1 = slot ^ ((srow1 >> 1) & 3);

#pragma unroll 1
    for (int f = 0; f < 33; ++f) {
        // ---- 1) stage B for this bin (prev barrier freed the buffers) ----
#pragma unroll
        for (int st = 0; st < 2; ++st) {
            const size_t gcol = (size_t)(2 * f + st) * 64;
#pragma unroll
            for (int pl = 0; pl < 2; ++pl) {
                const char* src = (const char*)(pl ? WpPL : WpPH);
                char* dst = lds + OFF_B + (st * 2 + pl) * 16384;
                gload16(src + (size_t)srow0 * (FD_ * 2) + gcol + (size_t)(kc0 * 16),
                        dst + tid * 16);
                gload16(src + (size_t)srow1 * (FD_ * 2) + gcol + (size_t)(kc1 * 16),
                        dst + (tid + 512) * 16);
            }
        }
        // ---- 2) gen bin f: init DFT + 8 slides, hides B-load latency ----
        float re = 0.f, im = 0.f;
        {
            int m = 0;
#pragma unroll
            for (int k = 0; k < 64; ++k) {
                const float2 wv = stabv[m];   // lane-uniform -> broadcast
                m = (m + f) & 63;
                re = fmaf(xr[k], wv.x, re);
                im = fmaf(xr[k], wv.y, im);
            }
        }
        const float cx = stabv[f].x, sx = -stabv[f].y;  // e^{+i pi f/32}
#pragma unroll
        for (int jj = 0; jj < 8; ++jj) {
            const int row = ws + jj;
            float mag, ph;
            if (f == 32) {                    // Nyquist: exact-real bin
                mag = flog1p(fabsf(re));
                ph  = (re < 0.f) ? 1.0f : 0.0f;
            } else {
                mag = flog1p(__builtin_amdgcn_sqrtf(fmaf(re, re, im * im)));
                ph  = fatan2pi(im, re);
            }
            const int ab = row * 64 + ((((cch >> 3) ^ ((row >> 1) & 3))) << 4)
                         + (cch & 7) * 2;
            *(u16*)(lds + OFF_A  + ab) = f2bf(mag);
            *(u16*)(lds + OFF_A2 + ab) = f2bf(ph);
            const float tre = re - xr[jj] + xr[jj + 64];
            re = tre * cx - im * sx;
            im = tre * sx + im * cx;
        }
        __syncthreads();   // drains vmcnt (B) + lgkm (A writes), publishes

        // ---- 3) MFMA: 2 K-steps (mag, ph) ----
#pragma unroll
        for (int st = 0; st < 2; ++st) {
            const char* aB  = lds + OFF_A + st * 8192;
            const char* bhB = lds + OFF_B + (st * 2 + 0) * 16384;
            const char* blB = lds + OFF_B + (st * 2 + 1) * 16384;
            bf16x8 ah[4], bh[4], bl[4];
#pragma unroll
            for (int fm = 0; fm < 4; ++fm) {
                const int r = wr * 64 + (lane & 15) + fm * 16;
                ah[fm] = *(const bf16x8*)(aB + r * 64 +
                          (((lane >> 4) ^ ((r >> 1) & 3)) << 4));
            }
#pragma unroll
            for (int fn = 0; fn < 4; ++fn) {
                const int r = wc * 64 + (lane & 15) + fn * 16;
                const int byt = r * 64 + (((lane >> 4) ^ ((r >> 1) & 3)) << 4);
                bh[fn] = *(const bf16x8*)(bhB + byt);
                bl[fn] = *(const bf16x8*)(blB + byt);
            }
#pragma unroll
            for (int fm = 0; fm < 4; ++fm)
#pragma unroll
                for (int fn = 0; fn < 4; ++fn) {
                    acc[fm][fn] = __builtin_amdgcn_mfma_f32_16x16x32_bf16(ah[fm], bh[fn], acc[fm][fn], 0, 0, 0);
                    acc[fm][fn] = __builtin_amdgcn_mfma_f32_16x16x32_bf16(ah[fm], bl[fn], acc[fm][fn], 0, 0, 0);
                }
        }
        __syncthreads();   // all waves done reading before next overwrite
    }

    // ---- epilogue ----
    float bv[4];
#pragma unroll
    for (int fn = 0; fn < 4; ++fn) bv[fn] = bp[wc * 64 + fn * 16 + (lane & 15)];
#pragma unroll
    for (int fm = 0; fm < 4; ++fm) {
#pragma unroll
        for (int fn = 0; fn < 4; ++fn) {
            const int col = wc * 64 + fn * 16 + (lane & 15);
#pragma unroll
            for (int r = 0; r < 4; ++r) {
                const int rl = wr * 64 + fm * 16 + (lane >> 4) * 4 + r;
                if (rl < mval) {
                    const size_t grow = (size_t)bb * NW_ + n0 + rl;
                    const float v = ftanh(acc[fm][fn][r] + bv[fn]) * PI_F;
                    const u16 h = f2bf(v);
                    projH[grow * 256 + col] = h;
                    projL[grow * 256 + col] = f2bf(v - bf2f(h));
                }
            }
        }
    }
}

// ---------------------------------------------------------------------------
// gemm2ph (round-5 kernel): 2-phase dbuf MFMA GEMM, BM=128 x BN=256, BK=32,
// 512 threads / 8 waves. Used for h1 (3-term, K=256).
// ---------------------------------------------------------------------------
template<bool HAS_AL>
__global__ __launch_bounds__(512, 2) void gemm2ph_kernel(
        const u16* __restrict__ AH, const u16* __restrict__ AL,
        const u16* __restrict__ BH, const u16* __restrict__ BL,
        const float* __restrict__ bias, float scale,
        u16* __restrict__ outH, u16* __restrict__ outL,
        int Mvalid, int Kd) {
    const int bm = blockIdx.x;
    const int tid = threadIdx.x;
    const int lane = tid & 63, w = tid >> 6;
    const int wr = w >> 2, wc = w & 3;
    const int m0 = bm * 128;

    constexpr int offB = HAS_AL ? 32768 : 16384;
    __shared__ char sA[offB + 65536];

    f32x4 acc[4][4];
#pragma unroll
    for (int i = 0; i < 4; ++i)
#pragma unroll
        for (int j = 0; j < 4; ++j) acc[i][j] = (f32x4){0.f, 0.f, 0.f, 0.f};

    const size_t rs = (size_t)Kd * 2;
    const char* gAH = (const char*)AH + (size_t)m0 * rs;
    const char* gAL = (const char*)AL + (size_t)m0 * rs;
    const char* gBH = (const char*)BH;
    const char* gBL = (const char*)BL;

    const int arow = tid >> 2, akc = tid & 3;
    const size_t aswz = (size_t)((akc ^ (arow & 3)) << 4);
    const int brow0 = tid >> 2;
    const int brow1 = (tid + 512) >> 2;
    const size_t bswz0 = (size_t)(((tid & 3) ^ (brow0 & 3)) << 4);
    const size_t bswz1 = (size_t)(((tid & 3) ^ (brow1 & 3)) << 4);

    const int sl = (((lane >> 4) ^ (lane & 3)) << 4);
    const int abase = (wr * 64 + (lane & 15)) * 64 + sl;
    const int bbase = (wc * 64 + (lane & 15)) * 64 + sl;

    const int nt = Kd >> 5;

    auto stage = [&](int buf, int t) {
        const size_t k0b = (size_t)t * 64;
        gload16(gAH + (size_t)arow * rs + k0b + aswz,
                sA + buf * 8192 + tid * 16);
        if constexpr (HAS_AL)
            gload16(gAL + (size_t)arow * rs + k0b + aswz,
                    sA + 16384 + buf * 8192 + tid * 16);
        gload16(gBH + (size_t)brow0 * rs + k0b + bswz0,
                sA + offB + buf * 16384 + tid * 16);
        gload16(gBH + (size_t)brow1 * rs + k0b + bswz1,
                sA + offB + buf * 16384 + (tid + 512) * 16);
        gload16(gBL + (size_t)brow0 * rs + k0b + bswz0,
                sA + offB + 32768 + buf * 16384 + tid * 16);
        gload16(gBL + (size_t)brow1 * rs + k0b + bswz1,
                sA + offB + 32768 + buf * 16384 + (tid + 512) * 16);
    };

    stage(0, 0);
    __syncthreads();

    int cur = 0;
    for (int t = 0; t < nt; ++t) {
        if (t + 1 < nt) stage(cur ^ 1, t + 1);

        const char* aBuf  = sA + cur * 8192;
        const char* alBuf = sA + 16384 + cur * 8192;
        const char* bhBuf = sA + offB + cur * 16384;
        const char* blBuf = sA + offB + 32768 + cur * 16384;

        bf16x8 ah[4], al[4], bh[4], bl[4];
#pragma unroll
        for (int f = 0; f < 4; ++f) {
            ah[f] = *(const bf16x8*)(aBuf + abase + f * 1024);
            if constexpr (HAS_AL) al[f] = *(const bf16x8*)(alBuf + abase + f * 1024);
            bh[f] = *(const bf16x8*)(bhBuf + bbase + f * 1024);
            bl[f] = *(const bf16x8*)(blBuf + bbase + f * 1024);
        }
#pragma unroll
        for (int fm = 0; fm < 4; ++fm)
#pragma unroll
            for (int fn = 0; fn < 4; ++fn) {
                acc[fm][fn] = __builtin_amdgcn_mfma_f32_16x16x32_bf16(ah[fm], bh[fn], acc[fm][fn], 0, 0, 0);
                acc[fm][fn] = __builtin_amdgcn_mfma_f32_16x16x32_bf16(ah[fm], bl[fn], acc[fm][fn], 0, 0, 0);
                if constexpr (HAS_AL)
                    acc[fm][fn] = __builtin_amdgcn_mfma_f32_16x16x32_bf16(al[fm], bh[fn], acc[fm][fn], 0, 0, 0);
            }
        __syncthreads();
        cur ^= 1;
    }

    float bv[4];
#pragma unroll
    for (int fn = 0; fn < 4; ++fn) bv[fn] = bias[wc * 64 + fn * 16 + (lane & 15)];
#pragma unroll
    for (int fm = 0; fm < 4; ++fm) {
        const int rbase = m0 + wr * 64 + fm * 16 + (lane >> 4) * 4;
#pragma unroll
        for (int fn = 0; fn < 4; ++fn) {
            const int col = wc * 64 + fn * 16 + (lane & 15);
#pragma unroll
            for (int r = 0; r < 4; ++r) {
                const int row = rbase + r;
                if (row < Mvalid) {
                    const float v = ftanh(acc[fm][fn][r] + bv[fn]) * scale;
                    const u16 h = f2bf(v);
                    outH[(size_t)row * 256 + col] = h;
                    outL[(size_t)row * 256 + col] = f2bf(v - bf2f(h));
                }
            }
        }
    }
}

// ---------------------------------------------------------------------------
// gemm_mfma (round-4/5 kernel): single-buffered 128x128, used for h2 (N=128).
// ---------------------------------------------------------------------------
template<bool HAS_AL, int OUT_BF16>
__global__ __launch_bounds__(256) void gemm_mfma_kernel(
        const u16* __restrict__ AH, const u16* __restrict__ AL,
        const u16* __restrict__ BH, const u16* __restrict__ BL,
        const float* __restrict__ bias, float scale,
        float* __restrict__ outF, u16* __restrict__ outH, u16* __restrict__ outL,
        int Mvalid, int N, int Kd) {
    const int bm = blockIdx.x, bn = blockIdx.y;
    const int tid = threadIdx.x;
    const int lane = tid & 63, w = tid >> 6;
    const int wr = w >> 1, wc = w & 1;
    const int m0 = bm * 128, n0 = bn * 128;

    __shared__ u16 smem[16384];
    char* sA = (char*)smem;

    f32x4 acc[4][4];
#pragma unroll
    for (int i = 0; i < 4; ++i)
#pragma unroll
        for (int j = 0; j < 4; ++j) acc[i][j] = (f32x4){0.f, 0.f, 0.f, 0.f};

    const size_t rs = (size_t)Kd * 2;
    const char* gAH = (const char*)AH + (size_t)m0 * rs;
    const char* gAL = (const char*)AL + (size_t)m0 * rs;
    const char* gBH = (const char*)BH + (size_t)n0 * rs;
    const char* gBL = (const char*)BL + (size_t)n0 * rs;

    const int r0 = tid >> 2;
    const int kbs = (((tid & 3) ^ ((tid >> 2) & 3)) << 4);
    const int loff0 = tid * 16;
    const int sl = (((lane >> 4) ^ (lane & 3)) << 4);
    const int abase = (wr * 64 + (lane & 15)) * 64 + sl;
    const int bbase = (wc * 64 + (lane & 15)) * 64 + sl;

    for (int k0b = 0; k0b < Kd * 2; k0b += 64) {
#pragma unroll
        for (int i = 0; i < 2; ++i) {
            const size_t go = (size_t)(r0 + i * 64) * rs + (size_t)(k0b + kbs);
            const int lo = loff0 + i * 4096;
            gload16(gAH + go, sA + lo);
            if constexpr (HAS_AL) gload16(gAL + go, sA + 8192 + lo);
            gload16(gBH + go, sA + 16384 + lo);
            gload16(gBL + go, sA + 24576 + lo);
        }
        __syncthreads();

        bf16x8 ah[4], al[4], bh[4], bl[4];
#pragma unroll
        for (int f = 0; f < 4; ++f) {
            ah[f] = *(const bf16x8*)(sA + abase + f * 1024);
            if constexpr (HAS_AL) al[f] = *(const bf16x8*)(sA + 8192 + abase + f * 1024);
            bh[f] = *(const bf16x8*)(sA + 16384 + bbase + f * 1024);
            bl[f] = *(const bf16x8*)(sA + 24576 + bbase + f * 1024);
        }
#pragma unroll
        for (int fm = 0; fm < 4; ++fm)
#pragma unroll
            for (int fn = 0; fn < 4; ++fn) {
                acc[fm][fn] = __builtin_amdgcn_mfma_f32_16x16x32_bf16(ah[fm], bh[fn], acc[fm][fn], 0, 0, 0);
                acc[fm][fn] = __builtin_amdgcn_mfma_f32_16x16x32_bf16(ah[fm], bl[fn], acc[fm][fn], 0, 0, 0);
                if constexpr (HAS_AL)
                    acc[fm][fn] = __builtin_amdgcn_mfma_f32_16x16x32_bf16(al[fm], bh[fn], acc[fm][fn], 0, 0, 0);
            }
        __syncthreads();
    }

    float bv[4];
#pragma unroll
    for (int fn = 0; fn < 4; ++fn) bv[fn] = bias[n0 + wc * 64 + fn * 16 + (lane & 15)];
#pragma unroll
    for (int fm = 0; fm < 4; ++fm) {
        const int rbase = m0 + wr * 64 + fm * 16 + (lane >> 4) * 4;
#pragma unroll
        for (int fn = 0; fn < 4; ++fn) {
            const int col = n0 + wc * 64 + fn * 16 + (lane & 15);
#pragma unroll
            for (int r = 0; r < 4; ++r) {
                const int row = rbase + r;
                if (row < Mvalid) {
                    const float v = ftanh(acc[fm][fn][r] + bv[fn]) * scale;
                    if constexpr (OUT_BF16) {
                        const u16 h = f2bf(v);
                        outH[(size_t)row * N + col] = h;
                        outL[(size_t)row * N + col] = f2bf(v - bf2f(h));
                    } else {
                        outF[(size_t)row * N + col] = v;
                    }
                }
            }
        }
    }
}

// ---------------------------------------------------------------------------
// out_reduce: per b, out[b] = sum_n (h2[b,n,:]·Wout + bout) * wts[n]
// ---------------------------------------------------------------------------
__global__ __launch_bounds__(256) void out_reduce_kernel(const float* __restrict__ h2,
                                                         const float* __restrict__ Wout,
                                                         const float* __restrict__ bout,
                                                         const float* __restrict__ wts,
                                                         float* __restrict__ out) {
    const int bb = blockIdx.x;
    const int tid = threadIdx.x;
    __shared__ float wsh[HH_];
    __shared__ float red[256];
    if (tid < HH_) wsh[tid] = Wout[tid];
    __syncthreads();
    const float bo = bout[0];
    float acc = 0.f;
    for (int n = tid; n < NW_; n += 256) {
        const float* row = h2 + ((size_t)bb * NW_ + n) * HH_;
        float dot = 0.f;
#pragma unroll
        for (int j = 0; j < HH_; j += 4) {
            const float4 v = *(const float4*)(row + j);
            dot += v.x * wsh[j] + v.y * wsh[j + 1] + v.z * wsh[j + 2] + v.w * wsh[j + 3];
        }
        acc += (dot + bo) * wts[n];
    }
    red[tid] = acc;
    __syncthreads();
    for (int s = 128; s > 0; s >>= 1) {
        if (tid < s) red[tid] += red[tid + s];
        __syncthreads();
    }
    if (tid == 0) out[bb] = red[0];
}

// ---------------------------------------------------------------------------
extern "C" void kernel_launch(void* const* d_in, const int* in_sizes, int n_in,
                              void* d_out, int out_size, void* d_ws, size_t ws_size,
                              hipStream_t stream) {
    const float* x    = (const float*)d_in[0];
    const float* Wp   = (const float*)d_in[1];
    const float* bp   = (const float*)d_in[2];
    const float* W1   = (const float*)d_in[3];
    const float* b1   = (const float*)d_in[4];
    const float* W2   = (const float*)d_in[5];
    const float* b2   = (const float*)d_in[6];
    const float* Wout = (const float*)d_in[7];
    const float* bout = (const float*)d_in[8];
    const float* agg  = (const float*)d_in[9];
    float* out = (float*)d_out;

    char* wsb = (char*)d_ws;
    size_t off = 0;
    auto ra = [](size_t b) { return (b + 255) & ~(size_t)255; };
    auto alloc = [&](size_t bytes) -> char* {
        char* p = wsb + off;
        off += ra(bytes);
        return p;
    };

    u16* WpPH = (u16*)alloc((size_t)MLP_ * FD_ * 2);   // K-permuted
    u16* WpPL = (u16*)alloc((size_t)MLP_ * FD_ * 2);
    u16* W1H  = (u16*)alloc((size_t)HID_ * MLP_ * 2);
    u16* W1L  = (u16*)alloc((size_t)HID_ * MLP_ * 2);
    u16* W2H  = (u16*)alloc((size_t)HH_ * HID_ * 2);
    u16* W2L  = (u16*)alloc((size_t)HH_ * HID_ * 2);
    float* wts = (float*)alloc((size_t)NW_ * 4);

    const size_t fixed = off;
    int NB = 32;
    for (;;) {
        const size_t M = (size_t)NB * NW_;
        const size_t Mp = ((M + 127) / 128) * 128;
        const size_t need = 4 * ra(Mp * 256 * 2) +    // projH/L, h1H/L
                            ra(Mp * 128 * 4);         // h2
        if (fixed + need <= ws_size || NB == 1) break;
        NB >>= 1;
    }
    const size_t Mmax  = (size_t)NB * NW_;
    const size_t MpMax = ((Mmax + 127) / 128) * 128;
    u16* projH = (u16*)alloc(MpMax * 256 * 2);
    u16* projL = (u16*)alloc(MpMax * 256 * 2);
    u16* h1H   = (u16*)alloc(MpMax * 256 * 2);
    u16* h1L   = (u16*)alloc(MpMax * 256 * 2);
    float* h2  = (float*)alloc(MpMax * 128 * 4);

    wconvP_kernel<<<dim3(512), dim3(256), 0, stream>>>(Wp, WpPH, WpPL);
    wconv_kernel<<<dim3(32),  dim3(256), 0, stream>>>(W1, W1H, W1L, HID_ * MLP_);
    wconv_kernel<<<dim3(16),  dim3(256), 0, stream>>>(W2, W2H, W2L, HH_ * HID_);
    softmax_kernel<<<dim3(1), dim3(256), 0, stream>>>(agg, wts);

    for (int b0 = 0; b0 < B_; b0 += NB) {
        const int nb = (B_ - b0 < NB) ? (B_ - b0) : NB;
        const int M = nb * NW_;
        const int Mp = ((M + 127) / 128) * 128;

        // fused feat+proj: tanh(feat @ Wp^T + bp)*pi, no feat materialization
        fused_feat_proj_kernel<<<dim3(8, nb), dim3(512), 0, stream>>>(
            x + (size_t)b0 * C_ * T_, WpPH, WpPL, bp, projH, projL);

        // h1: tanh(proj @ W1^T + b1)   (3-term, K=256)
        gemm2ph_kernel<true><<<dim3(Mp / 128), dim3(512), 0, stream>>>(
            projH, projL, W1H, W1L, b1, 1.0f, h1H, h1L, M, MLP_);

        // h2: tanh(h1 @ W2^T + b2), fp32 out (3-term, N=128)
        gemm_mfma_kernel<true, 0><<<dim3(Mp / 128, 1), dim3(256), 0, stream>>>(
            h1H, h1L, W2H, W2L, b2, 1.0f, h2, nullptr, nullptr, M, HH_, HID_);

        out_reduce_kernel<<<dim3(nb), dim3(256), 0, stream>>>(
            h2, Wout, bout, wts, out + b0);
    }
}

// Round 8
// 204.846 us; speedup vs baseline: 1.2456x; 1.2456x over previous
//
#include <hip/hip_runtime.h>
#include <math.h>

#define B_   32
#define C_   32
#define T_   1024
#define NF_  33
#define F2_  66      // NF*2
#define FD_  2112    // C_*F2_
#define NW_  961
#define MLP_ 256
#define HID_ 256
#define HH_  128
#define TN_  32
#define NT_  31      // ceil(961/32)

#define PI_F     3.14159265358979323846f
#define LN2_F    0.69314718055994530942f
#define L2E2_F   2.88539008177792681472f   // 2*log2(e)

typedef unsigned short u16;
typedef unsigned int   u32;
typedef __attribute__((ext_vector_type(8))) short bf16x8;
typedef __attribute__((ext_vector_type(4))) float f32x4;

__device__ __forceinline__ u16 f2bf(float f) {
    u32 u = __float_as_uint(f);
    u = u + 0x7FFFu + ((u >> 16) & 1u);   // RNE
    return (u16)(u >> 16);
}
__device__ __forceinline__ float bf2f(u16 h) {
    return __uint_as_float((u32)h << 16);
}
__device__ __forceinline__ void gload16(const void* g, void* l) {
    __builtin_amdgcn_global_load_lds(
        (const __attribute__((address_space(1))) void*)g,
        (__attribute__((address_space(3))) void*)l, 16, 0, 0);
}
__device__ __forceinline__ float ftanh(float x) {
    float z = __builtin_amdgcn_exp2f(x * L2E2_F);
    return 1.f - 2.f * __builtin_amdgcn_rcpf(z + 1.f);
}
__device__ __forceinline__ float flog1p(float x) {
    return __builtin_amdgcn_logf(1.f + x) * LN2_F;   // v_log_f32 is log2
}
// atan2(y,x)/pi, poly max err ~2e-6 (in pi units)
__device__ __forceinline__ float fatan2pi(float y, float x) {
    const float ay = fabsf(y), ax = fabsf(x);
    const float mn = fminf(ay, ax), mx = fmaxf(ay, ax);
    float t = mn * __builtin_amdgcn_rcpf(mx);
    t = (mx == 0.f) ? 0.f : t;
    const float s = t * t;
    float p = -0.00373098f;
    p = fmaf(p, s,  0.01676008f);
    p = fmaf(p, s, -0.03706162f);
    p = fmaf(p, s,  0.06160679f);
    p = fmaf(p, s, -0.10587735f);
    p = fmaf(p, s,  0.31830265f);
    p *= t;
    p = (ay > ax) ? 0.5f - p : p;
    p = (x < 0.f) ? 1.0f - p : p;
    return copysignf(p, y);
}

// ---------------------------------------------------------------------------
// wconv: fp32 weight matrix -> bf16 hi/lo planes (same layout)
// ---------------------------------------------------------------------------
__global__ __launch_bounds__(256) void wconv_kernel(const float* __restrict__ W,
                                                    u16* __restrict__ WH,
                                                    u16* __restrict__ WL,
                                                    int total) {
    for (int i = blockIdx.x * 256 + threadIdx.x; i < total; i += gridDim.x * 256) {
        const float v = W[i];
        const u16 h = f2bf(v);
        WH[i] = h;
        WL[i] = f2bf(v - bf2f(h));
    }
}

// ---------------------------------------------------------------------------
// softmax(agg) -> wts (single block)
// ---------------------------------------------------------------------------
__global__ __launch_bounds__(256) void softmax_kernel(const float* __restrict__ agg,
                                                      float* __restrict__ wts) {
    const int tid = threadIdx.x;
    __shared__ float red[256];
    float mx = -INFINITY;
    for (int i = tid; i < NW_; i += 256) mx = fmaxf(mx, agg[i]);
    red[tid] = mx; __syncthreads();
    for (int s = 128; s > 0; s >>= 1) {
        if (tid < s) red[tid] = fmaxf(red[tid], red[tid + s]);
        __syncthreads();
    }
    mx = red[0]; __syncthreads();
    float sm = 0.f;
    for (int i = tid; i < NW_; i += 256) sm += expf(agg[i] - mx);
    red[tid] = sm; __syncthreads();
    for (int s = 128; s > 0; s >>= 1) {
        if (tid < s) red[tid] += red[tid + s];
        __syncthreads();
    }
    const float inv = 1.f / red[0];
    for (int i = tid; i < NW_; i += 256) wts[i] = expf(agg[i] - mx) * inv;
}

// ---------------------------------------------------------------------------
// feat v3: SLIDING DFT (round-5 version, unchanged).
// ---------------------------------------------------------------------------
__global__ __launch_bounds__(256) void feat_kernel(const float* __restrict__ x,
                                                   u32* __restrict__ featP) {
    const int n0 = blockIdx.x * TN_;
    const int cg = blockIdx.y;
    const int bb = blockIdx.z;
    const int tid = threadIdx.x;
    const int tf = tid & 31;     // bin 0..31
    const int c8 = tid >> 5;     // channel-in-group 0..7
    const int c  = cg * 8 + c8;

    __shared__ float2 stab[64];
    __shared__ float xs[8][96];
    __shared__ float basisT[64][68];

    if (tid < 64) {
        float s, cc;
        sincosf(-PI_F * (float)tid / 32.0f, &s, &cc);
        stab[tid] = make_float2(cc, s);
    }
    __syncthreads();
    for (int e = tid; e < 2048; e += 256) {
        const int f = e >> 6, k = e & 63;
        const float2 w = stab[(f * k) & 63];
        basisT[k][2 * f]     = w.x;
        basisT[k][2 * f + 1] = w.y;
    }
    if (tid < 192) {
        const int cs = tid / 24, q = tid % 24;
        const int t0 = n0 + q * 4;
        const float* xb = x + ((size_t)bb * C_ + cg * 8 + cs) * T_;
        float4 v;
        if (t0 + 3 < T_) {
            v = *(const float4*)(xb + t0);
        } else {
            v.x = (t0 + 0 < T_) ? xb[t0 + 0] : 0.f;
            v.y = (t0 + 1 < T_) ? xb[t0 + 1] : 0.f;
            v.z = (t0 + 2 < T_) ? xb[t0 + 2] : 0.f;
            v.w = 0.f;
        }
        *(float4*)&xs[cs][q * 4] = v;
    }
    __syncthreads();

    const size_t rowb = (size_t)bb * NW_;

    // ---- phase 1: bins 0..31, sliding across 32 windows ----
    {
        float re = 0.f, im = 0.f;
#pragma unroll
        for (int k = 0; k < 64; ++k) {
            const float xv = xs[c8][k];
            const float2 w = *(const float2*)&basisT[k][2 * tf];
            re = fmaf(xv, w.x, re);
            im = fmaf(xv, w.y, im);
        }
        const float2 st = stab[tf];
        const float cx = st.x, sx = -st.y;

        for (int j = 0; j < TN_; ++j) {
            const int gn = n0 + j;
            if (gn >= NW_) break;
            const float r   = __builtin_amdgcn_sqrtf(re * re + im * im);
            const float mag = flog1p(r);
            const float ph  = fatan2pi(im, re);
            featP[(rowb + gn) * (FD_ / 2) + 33 * c + tf] =
                (u32)f2bf(mag) | ((u32)f2bf(ph) << 16);
            const float tre = re - xs[c8][j] + xs[c8][j + 64];
            re = tre * cx - im * sx;
            im = tre * sx + im * cx;
        }
    }

    // ---- phase 2: Nyquist bin ----
    {
        const int j   = tid & 31;
        const int c8n = tid >> 5;
        const int gn  = n0 + j;
        if (gn < NW_) {
            float s = 0.f;
#pragma unroll
            for (int k = 0; k < 32; ++k)
                s += xs[c8n][j + 2 * k] - xs[c8n][j + 2 * k + 1];
            const float a = flog1p(fabsf(s));
            const float p = (__float_as_uint(s) >> 31) ? 1.0f : 0.0f;
            featP[(rowb + gn) * (FD_ / 2) + 33 * (cg * 8 + c8n) + 32] =
                (u32)f2bf(a) | ((u32)f2bf(p) << 16);
        }
    }
}

// ---------------------------------------------------------------------------
// proj3b: 3-buffer depth-2 counted-vmcnt pipeline (round-6 schedule) at
// BM=128 x BN=256 (A fetched once). BK=32, 512 thr / 8 waves (2x4 of 64x64).
// Per K-step: {s_waitcnt vmcnt(5|0); s_barrier; stage(t+2); compute(t)}.
// 5 gload16/thread/step (A hi 8KB, B hi 16KB, B lo 16KB = 40KB). LDS 120KB.
// Swizzle slot = kc ^ ((row>>1)&3) both sides (round-6: 0 bank conflicts).
// proj = tanh(feat @ Wp^T + bp) * pi -> bf16 hi/lo planes.
// ---------------------------------------------------------------------------
__global__ __launch_bounds__(512, 2) void proj3b_kernel(
        const u16* __restrict__ AH,
        const u16* __restrict__ BH, const u16* __restrict__ BL,
        const float* __restrict__ bias,
        u16* __restrict__ outH, u16* __restrict__ outL, int Mvalid) {
    constexpr int STEPB = 40960;           // A 8K | Bh 16K | Bl 16K
    __shared__ char lds[3 * STEPB];        // 120 KB

    const int bm = blockIdx.x;
    const int tid = threadIdx.x;
    const int lane = tid & 63, w = tid >> 6;
    const int wr = w >> 2, wc = w & 3;     // 2 x 4 waves of 64x64
    const int m0 = bm * 128;

    f32x4 acc[4][4];
#pragma unroll
    for (int i = 0; i < 4; ++i)
#pragma unroll
        for (int j = 0; j < 4; ++j) acc[i][j] = (f32x4){0.f, 0.f, 0.f, 0.f};

    const size_t rs = (size_t)FD_ * 2;
    const char* gA  = (const char*)AH + (size_t)m0 * rs;
    const char* gBH = (const char*)BH;
    const char* gBL = (const char*)BL;

    // one 16B chunk: linear LDS slot, pre-swizzled global source (involution)
    auto st1 = [&](const char* g, char* l, int idx) {
        const int row = idx >> 2;
        const int kc  = (idx & 3) ^ ((row >> 1) & 3);
        gload16(g + (size_t)row * rs + (size_t)(kc << 4), l + idx * 16);
    };
    auto stage = [&](int buf, int t) {
        const size_t k0b = (size_t)t << 6;          // t*64 bytes
        char* lb = lds + buf * STEPB;
        st1(gA  + k0b, lb,         tid);            // A: 512 chunks
        st1(gBH + k0b, lb + 8192,  tid);            // B: 1024 chunks/plane
        st1(gBH + k0b, lb + 8192,  tid + 512);
        st1(gBL + k0b, lb + 24576, tid);
        st1(gBL + k0b, lb + 24576, tid + 512);
    };

    // read-side fragment addressing (swizzle invariant under row += 16)
    const int ra_ = wr * 64 + (lane & 15);
    const int rb_ = wc * 64 + (lane & 15);
    const int q   = lane >> 4;
    const int abase = ra_ * 64 + ((q ^ ((ra_ >> 1) & 3)) << 4);
    const int bbase = rb_ * 64 + ((q ^ ((rb_ >> 1) & 3)) << 4);

    const int nt = FD_ / 32;   // 66

    stage(0, 0);
    stage(1, 1);

    int cur = 0;
    for (int t = 0; t < nt; ++t) {
        if (t + 1 < nt)
            asm volatile("s_waitcnt vmcnt(5)" ::: "memory");
        else
            asm volatile("s_waitcnt vmcnt(0)" ::: "memory");
        __builtin_amdgcn_sched_barrier(0);
        __builtin_amdgcn_s_barrier();
        asm volatile("" ::: "memory");

        int pf = cur + 2; if (pf >= 3) pf -= 3;
        if (t + 2 < nt) stage(pf, t + 2);

        const char* lb = lds + cur * STEPB;
        bf16x8 ah[4], bh[4], bl[4];
#pragma unroll
        for (int f = 0; f < 4; ++f) {
            ah[f] = *(const bf16x8*)(lb + abase + f * 1024);
            bh[f] = *(const bf16x8*)(lb + 8192  + bbase + f * 1024);
            bl[f] = *(const bf16x8*)(lb + 24576 + bbase + f * 1024);
        }
#pragma unroll
        for (int fm = 0; fm < 4; ++fm)
#pragma unroll
            for (int fn = 0; fn < 4; ++fn) {
                acc[fm][fn] = __builtin_amdgcn_mfma_f32_16x16x32_bf16(ah[fm], bh[fn], acc[fm][fn], 0, 0, 0);
                acc[fm][fn] = __builtin_amdgcn_mfma_f32_16x16x32_bf16(ah[fm], bl[fn], acc[fm][fn], 0, 0, 0);
            }
        ++cur; if (cur >= 3) cur -= 3;
    }

    float bv[4];
#pragma unroll
    for (int fn = 0; fn < 4; ++fn) bv[fn] = bias[wc * 64 + fn * 16 + (lane & 15)];
#pragma unroll
    for (int fm = 0; fm < 4; ++fm) {
        const int rbase = m0 + wr * 64 + fm * 16 + (lane >> 4) * 4;
#pragma unroll
        for (int fn = 0; fn < 4; ++fn) {
            const int col = wc * 64 + fn * 16 + (lane & 15);
#pragma unroll
            for (int r = 0; r < 4; ++r) {
                const int row = rbase + r;
                if (row < Mvalid) {
                    const float v = ftanh(acc[fm][fn][r] + bv[fn]) * PI_F;
                    const u16 h = f2bf(v);
                    outH[(size_t)row * 256 + col] = h;
                    outL[(size_t)row * 256 + col] = f2bf(v - bf2f(h));
                }
            }
        }
    }
}

// ---------------------------------------------------------------------------
// gemm2ph: 2-phase dbuf MFMA GEMM, BM=128 x BN=256, BK=32, 512 thr / 8 waves.
// Used for h1 (3-term, K=256). Swizzle fixed to (row>>1)&3 (2-way free).
// ---------------------------------------------------------------------------
template<bool HAS_AL>
__global__ __launch_bounds__(512, 2) void gemm2ph_kernel(
        const u16* __restrict__ AH, const u16* __restrict__ AL,
        const u16* __restrict__ BH, const u16* __restrict__ BL,
        const float* __restrict__ bias, float scale,
        u16* __restrict__ outH, u16* __restrict__ outL,
        int Mvalid, int Kd) {
    const int bm = blockIdx.x;
    const int tid = threadIdx.x;
    const int lane = tid & 63, w = tid >> 6;
    const int wr = w >> 2, wc = w & 3;
    const int m0 = bm * 128;

    constexpr int offB = HAS_AL ? 32768 : 16384;
    __shared__ char sA[offB + 65536];

    f32x4 acc[4][4];
#pragma unroll
    for (int i = 0; i < 4; ++i)
#pragma unroll
        for (int j = 0; j < 4; ++j) acc[i][j] = (f32x4){0.f, 0.f, 0.f, 0.f};

    const size_t rs = (size_t)Kd * 2;
    const char* gAH = (const char*)AH + (size_t)m0 * rs;
    const char* gAL = (const char*)AL + (size_t)m0 * rs;
    const char* gBH = (const char*)BH;
    const char* gBL = (const char*)BL;

    const int arow = tid >> 2;
    const size_t aswz = (size_t)(((tid & 3) ^ ((arow >> 1) & 3)) << 4);
    const int brow0 = tid >> 2;
    const int brow1 = brow0 + 128;
    const size_t bswz0 = (size_t)(((tid & 3) ^ ((brow0 >> 1) & 3)) << 4);
    const size_t bswz1 = (size_t)(((tid & 3) ^ ((brow1 >> 1) & 3)) << 4);

    const int sl = (((lane >> 4) ^ ((lane >> 1) & 3)) << 4);
    const int abase = (wr * 64 + (lane & 15)) * 64 + sl;
    const int bbase = (wc * 64 + (lane & 15)) * 64 + sl;

    const int nt = Kd >> 5;

    auto stage = [&](int buf, int t) {
        const size_t k0b = (size_t)t * 64;
        gload16(gAH + (size_t)arow * rs + k0b + aswz,
                sA + buf * 8192 + tid * 16);
        if constexpr (HAS_AL)
            gload16(gAL + (size_t)arow * rs + k0b + aswz,
                    sA + 16384 + buf * 8192 + tid * 16);
        gload16(gBH + (size_t)brow0 * rs + k0b + bswz0,
                sA + offB + buf * 16384 + tid * 16);
        gload16(gBH + (size_t)brow1 * rs + k0b + bswz1,
                sA + offB + buf * 16384 + (tid + 512) * 16);
        gload16(gBL + (size_t)brow0 * rs + k0b + bswz0,
                sA + offB + 32768 + buf * 16384 + tid * 16);
        gload16(gBL + (size_t)brow1 * rs + k0b + bswz1,
                sA + offB + 32768 + buf * 16384 + (tid + 512) * 16);
    };

    stage(0, 0);
    __syncthreads();

    int cur = 0;
    for (int t = 0; t < nt; ++t) {
        if (t + 1 < nt) stage(cur ^ 1, t + 1);

        const char* aBuf  = sA + cur * 8192;
        const char* alBuf = sA + 16384 + cur * 8192;
        const char* bhBuf = sA + offB + cur * 16384;
        const char* blBuf = sA + offB + 32768 + cur * 16384;

        bf16x8 ah[4], al[4], bh[4], bl[4];
#pragma unroll
        for (int f = 0; f < 4; ++f) {
            ah[f] = *(const bf16x8*)(aBuf + abase + f * 1024);
            if constexpr (HAS_AL) al[f] = *(const bf16x8*)(alBuf + abase + f * 1024);
            bh[f] = *(const bf16x8*)(bhBuf + bbase + f * 1024);
            bl[f] = *(const bf16x8*)(blBuf + bbase + f * 1024);
        }
#pragma unroll
        for (int fm = 0; fm < 4; ++fm)
#pragma unroll
            for (int fn = 0; fn < 4; ++fn) {
                acc[fm][fn] = __builtin_amdgcn_mfma_f32_16x16x32_bf16(ah[fm], bh[fn], acc[fm][fn], 0, 0, 0);
                acc[fm][fn] = __builtin_amdgcn_mfma_f32_16x16x32_bf16(ah[fm], bl[fn], acc[fm][fn], 0, 0, 0);
                if constexpr (HAS_AL)
                    acc[fm][fn] = __builtin_amdgcn_mfma_f32_16x16x32_bf16(al[fm], bh[fn], acc[fm][fn], 0, 0, 0);
            }
        __syncthreads();
        cur ^= 1;
    }

    float bv[4];
#pragma unroll
    for (int fn = 0; fn < 4; ++fn) bv[fn] = bias[wc * 64 + fn * 16 + (lane & 15)];
#pragma unroll
    for (int fm = 0; fm < 4; ++fm) {
        const int rbase = m0 + wr * 64 + fm * 16 + (lane >> 4) * 4;
#pragma unroll
        for (int fn = 0; fn < 4; ++fn) {
            const int col = wc * 64 + fn * 16 + (lane & 15);
#pragma unroll
            for (int r = 0; r < 4; ++r) {
                const int row = rbase + r;
                if (row < Mvalid) {
                    const float v = ftanh(acc[fm][fn][r] + bv[fn]) * scale;
                    const u16 h = f2bf(v);
                    outH[(size_t)row * 256 + col] = h;
                    outL[(size_t)row * 256 + col] = f2bf(v - bf2f(h));
                }
            }
        }
    }
}

// ---------------------------------------------------------------------------
// gemm_mfma: single-buffered 128x128, used for h2 (N=128, fp32 out).
// Swizzle fixed to (row>>1)&3.
// ---------------------------------------------------------------------------
template<bool HAS_AL, int OUT_BF16>
__global__ __launch_bounds__(256) void gemm_mfma_kernel(
        const u16* __restrict__ AH, const u16* __restrict__ AL,
        const u16* __restrict__ BH, const u16* __restrict__ BL,
        const float* __restrict__ bias, float scale,
        float* __restrict__ outF, u16* __restrict__ outH, u16* __restrict__ outL,
        int Mvalid, int N, int Kd) {
    const int bm = blockIdx.x, bn = blockIdx.y;
    const int tid = threadIdx.x;
    const int lane = tid & 63, w = tid >> 6;
    const int wr = w >> 1, wc = w & 1;
    const int m0 = bm * 128, n0 = bn * 128;

    __shared__ u16 smem[16384];
    char* sA = (char*)smem;

    f32x4 acc[4][4];
#pragma unroll
    for (int i = 0; i < 4; ++i)
#pragma unroll
        for (int j = 0; j < 4; ++j) acc[i][j] = (f32x4){0.f, 0.f, 0.f, 0.f};

    const size_t rs = (size_t)Kd * 2;
    const char* gAH = (const char*)AH + (size_t)m0 * rs;
    const char* gAL = (const char*)AL + (size_t)m0 * rs;
    const char* gBH = (const char*)BH + (size_t)n0 * rs;
    const char* gBL = (const char*)BL + (size_t)n0 * rs;

    const int r0 = tid >> 2;
    const int kbs = (((tid & 3) ^ ((tid >> 3) & 3)) << 4);
    const int loff0 = tid * 16;
    const int sl = (((lane >> 4) ^ ((lane >> 1) & 3)) << 4);
    const int abase = (wr * 64 + (lane & 15)) * 64 + sl;
    const int bbase = (wc * 64 + (lane & 15)) * 64 + sl;

    for (int k0b = 0; k0b < Kd * 2; k0b += 64) {
#pragma unroll
        for (int i = 0; i < 2; ++i) {
            const size_t go = (size_t)(r0 + i * 64) * rs + (size_t)(k0b + kbs);
            const int lo = loff0 + i * 4096;
            gload16(gAH + go, sA + lo);
            if constexpr (HAS_AL) gload16(gAL + go, sA + 8192 + lo);
            gload16(gBH + go, sA + 16384 + lo);
            gload16(gBL + go, sA + 24576 + lo);
        }
        __syncthreads();

        bf16x8 ah[4], al[4], bh[4], bl[4];
#pragma unroll
        for (int f = 0; f < 4; ++f) {
            ah[f] = *(const bf16x8*)(sA + abase + f * 1024);
            if constexpr (HAS_AL) al[f] = *(const bf16x8*)(sA + 8192 + abase + f * 1024);
            bh[f] = *(const bf16x8*)(sA + 16384 + bbase + f * 1024);
            bl[f] = *(const bf16x8*)(sA + 24576 + bbase + f * 1024);
        }
#pragma unroll
        for (int fm = 0; fm < 4; ++fm)
#pragma unroll
            for (int fn = 0; fn < 4; ++fn) {
                acc[fm][fn] = __builtin_amdgcn_mfma_f32_16x16x32_bf16(ah[fm], bh[fn], acc[fm][fn], 0, 0, 0);
                acc[fm][fn] = __builtin_amdgcn_mfma_f32_16x16x32_bf16(ah[fm], bl[fn], acc[fm][fn], 0, 0, 0);
                if constexpr (HAS_AL)
                    acc[fm][fn] = __builtin_amdgcn_mfma_f32_16x16x32_bf16(al[fm], bh[fn], acc[fm][fn], 0, 0, 0);
            }
        __syncthreads();
    }

    float bv[4];
#pragma unroll
    for (int fn = 0; fn < 4; ++fn) bv[fn] = bias[n0 + wc * 64 + fn * 16 + (lane & 15)];
#pragma unroll
    for (int fm = 0; fm < 4; ++fm) {
        const int rbase = m0 + wr * 64 + fm * 16 + (lane >> 4) * 4;
#pragma unroll
        for (int fn = 0; fn < 4; ++fn) {
            const int col = n0 + wc * 64 + fn * 16 + (lane & 15);
#pragma unroll
            for (int r = 0; r < 4; ++r) {
                const int row = rbase + r;
                if (row < Mvalid) {
                    const float v = ftanh(acc[fm][fn][r] + bv[fn]) * scale;
                    if constexpr (OUT_BF16) {
                        const u16 h = f2bf(v);
                        outH[(size_t)row * N + col] = h;
                        outL[(size_t)row * N + col] = f2bf(v - bf2f(h));
                    } else {
                        outF[(size_t)row * N + col] = v;
                    }
                }
            }
        }
    }
}

// ---------------------------------------------------------------------------
// out_reduce: per b, out[b] = sum_n (h2[b,n,:]·Wout + bout) * wts[n]
// ---------------------------------------------------------------------------
__global__ __launch_bounds__(256) void out_reduce_kernel(const float* __restrict__ h2,
                                                         const float* __restrict__ Wout,
                                                         const float* __restrict__ bout,
                                                         const float* __restrict__ wts,
                                                         float* __restrict__ out) {
    const int bb = blockIdx.x;
    const int tid = threadIdx.x;
    __shared__ float wsh[HH_];
    __shared__ float red[256];
    if (tid < HH_) wsh[tid] = Wout[tid];
    __syncthreads();
    const float bo = bout[0];
    float acc = 0.f;
    for (int n = tid; n < NW_; n += 256) {
        const float* row = h2 + ((size_t)bb * NW_ + n) * HH_;
        float dot = 0.f;
#pragma unroll
        for (int j = 0; j < HH_; j += 4) {
            const float4 v = *(const float4*)(row + j);
            dot += v.x * wsh[j] + v.y * wsh[j + 1] + v.z * wsh[j + 2] + v.w * wsh[j + 3];
        }
        acc += (dot + bo) * wts[n];
    }
    red[tid] = acc;
    __syncthreads();
    for (int s = 128; s > 0; s >>= 1) {
        if (tid < s) red[tid] += red[tid + s];
        __syncthreads();
    }
    if (tid == 0) out[bb] = red[0];
}

// ---------------------------------------------------------------------------
extern "C" void kernel_launch(void* const* d_in, const int* in_sizes, int n_in,
                              void* d_out, int out_size, void* d_ws, size_t ws_size,
                              hipStream_t stream) {
    const float* x    = (const float*)d_in[0];
    const float* Wp   = (const float*)d_in[1];
    const float* bp   = (const float*)d_in[2];
    const float* W1   = (const float*)d_in[3];
    const float* b1   = (const float*)d_in[4];
    const float* W2   = (const float*)d_in[5];
    const float* b2   = (const float*)d_in[6];
    const float* Wout = (const float*)d_in[7];
    const float* bout = (const float*)d_in[8];
    const float* agg  = (const float*)d_in[9];
    float* out = (float*)d_out;

    char* wsb = (char*)d_ws;
    size_t off = 0;
    auto ra = [](size_t b) { return (b + 255) & ~(size_t)255; };
    auto alloc = [&](size_t bytes) -> char* {
        char* p = wsb + off;
        off += ra(bytes);
        return p;
    };

    u16* WpH = (u16*)alloc((size_t)MLP_ * FD_ * 2);
    u16* WpL = (u16*)alloc((size_t)MLP_ * FD_ * 2);
    u16* W1H = (u16*)alloc((size_t)HID_ * MLP_ * 2);
    u16* W1L = (u16*)alloc((size_t)HID_ * MLP_ * 2);
    u16* W2H = (u16*)alloc((size_t)HH_ * HID_ * 2);
    u16* W2L = (u16*)alloc((size_t)HH_ * HID_ * 2);
    float* wts = (float*)alloc((size_t)NW_ * 4);

    const size_t fixed = off;
    int NB = 32;
    for (;;) {
        const size_t M = (size_t)NB * NW_;
        const size_t Mp = ((M + 127) / 128) * 128;
        const size_t need = ra(Mp * FD_ * 2) +        // featH
                            4 * ra(Mp * 256 * 2) +    // projH/L, h1H/L
                            ra(Mp * 128 * 4);         // h2
        if (fixed + need <= ws_size || NB == 1) break;
        NB >>= 1;
    }
    const size_t Mmax  = (size_t)NB * NW_;
    const size_t MpMax = ((Mmax + 127) / 128) * 128;
    u16* featH = (u16*)alloc(MpMax * FD_ * 2);
    u16* projH = (u16*)alloc(MpMax * 256 * 2);
    u16* projL = (u16*)alloc(MpMax * 256 * 2);
    u16* h1H   = (u16*)alloc(MpMax * 256 * 2);
    u16* h1L   = (u16*)alloc(MpMax * 256 * 2);
    float* h2  = (float*)alloc(MpMax * 128 * 4);

    wconv_kernel<<<dim3(128), dim3(256), 0, stream>>>(Wp, WpH, WpL, MLP_ * FD_);
    wconv_kernel<<<dim3(32),  dim3(256), 0, stream>>>(W1, W1H, W1L, HID_ * MLP_);
    wconv_kernel<<<dim3(16),  dim3(256), 0, stream>>>(W2, W2H, W2L, HH_ * HID_);
    softmax_kernel<<<dim3(1), dim3(256), 0, stream>>>(agg, wts);

    for (int b0 = 0; b0 < B_; b0 += NB) {
        const int nb = (B_ - b0 < NB) ? (B_ - b0) : NB;
        const int M = nb * NW_;
        const int Mp = ((M + 127) / 128) * 128;

        feat_kernel<<<dim3(NT_, 4, nb), dim3(256), 0, stream>>>(
            x + (size_t)b0 * C_ * T_, (u32*)featH);

        // proj: tanh(feat @ Wp^T + bp)*pi  (2-term, K=2112, depth-2 pipeline)
        proj3b_kernel<<<dim3(Mp / 128), dim3(512), 0, stream>>>(
            featH, WpH, WpL, bp, projH, projL, M);

        // h1: tanh(proj @ W1^T + b1)   (3-term, K=256)
        gemm2ph_kernel<true><<<dim3(Mp / 128), dim3(512), 0, stream>>>(
            projH, projL, W1H, W1L, b1, 1.0f, h1H, h1L, M, MLP_);

        // h2: tanh(h1 @ W2^T + b2), fp32 out (3-term, N=128)
        gemm_mfma_kernel<true, 0><<<dim3(Mp / 128, 1), dim3(256), 0, stream>>>(
            h1H, h1L, W2H, W2L, b2, 1.0f, h2, nullptr, nullptr, M, HH_, HID_);

        out_reduce_kernel<<<dim3(nb), dim3(256), 0, stream>>>(
            h2, Wout, bout, wts, out + b0);
    }
}